// Round 15
// baseline (291.077 us; speedup 1.0000x reference)
//
#include <hip/hip_runtime.h>
#include <hip/hip_fp16.h>

// Kuramoto phase dynamics + coherence softmax. B*S=1024 rows, V=50257, 10 steps.
// Two-pass trajectory scheme (validated r11-r14, absmax 2.38e-7), stateless
// between passes (r14: VGPR=52, zero spill). Round-15 changes:
//  * Pass B algebra: eps_j = Im(z0_j * P(r_j)), P(r) = sum_t (dCt - i*dSt) r^t
//    evaluated by complex Horner (9 x 4 pk-fma, SGPR coefficients), and final
//    state z10 = z0 * r^10 via a second table (4 pk-fma) -- replaces the
//    10-step re-rotation + eps loop (-27% of B).
//  * Pass A: packed v2f accumulators (vS,vC) -> 6 pk-instr/pair-step (was 8).
//  * Occupancy: LDS stash cut to 25 stripes (51.9 KB) -> 3 blocks/CU
//    (24 waves) IF VGPR <= 85; 8 stripes stash in regs, 16 stash unscaled
//    into their own out slots (extra ~134 MB HBM round-trip, overlapped).
// Partition: 49 pair-stripes of 1024 elems (pairs (2tid, 2tid+1)) + 81-elem
// scalar tail. mean(p_final) = (Sum p0 + Sum omega)/V (sum_i eps_i == 0).

#define V_DIM   50257
#define NROWS   1024
#define NT      512
#define NS_LDS  25                // e stashed in LDS (f16 half2)
#define NS_REG  8                 // e stashed in regs (f32 v2f)
#define NS_OUT  16                // e stashed unscaled in own out slots
#define NSTOT   (NS_LDS + NS_REG + NS_OUT)   // 49
#define STRIDE  (2 * NT)          // 1024
#define TAIL_B  (NSTOT * STRIDE)  // 50176
#define TAILN   (V_DIM - TAIL_B)  // 81
#define NSTEP   10
#define INV2PI  0.15915494309189535f
#define DTC     (0.1f * (0.1f / (float)V_DIM))

typedef float v2f __attribute__((ext_vector_type(2)));

__device__ __forceinline__ float fsin(float r) { return __builtin_amdgcn_sinf(r); }
__device__ __forceinline__ float fcos(float r) { return __builtin_amdgcn_cosf(r); }
__device__ __forceinline__ float rfl(float x) {
    return __builtin_bit_cast(float, __builtin_amdgcn_readfirstlane(__builtin_bit_cast(int, x)));
}
#define FENCE() __builtin_amdgcn_sched_barrier(0)

__device__ __forceinline__ void rot1(float& s, float& c, const float ts, const float td) {
    float u = __builtin_fmaf(s, td, s); u = __builtin_fmaf(c, ts, u);
    float v = __builtin_fmaf(c, td, c); v = __builtin_fmaf(-s, ts, v);
    s = u; c = v;
}

// ---- ws[0] = sum(omega), deterministic single-block reduce ----
__global__ __launch_bounds__(1024) void sw_kernel(const float* __restrict__ om,
                                                  float* __restrict__ ws) {
    __shared__ float red[16];
    const int tid = threadIdx.x;
    float a = 0.f;
    for (int i = tid; i < V_DIM; i += 1024) a += om[i];
    #pragma unroll
    for (int off = 32; off > 0; off >>= 1) a += __shfl_xor(a, off, 64);
    if ((tid & 63) == 0) red[tid >> 6] = a;
    __syncthreads();
    if (tid == 0) {
        float t = 0.f;
        #pragma unroll
        for (int i = 0; i < 16; ++i) t += red[i];
        ws[0] = t;
    }
}

// tblR[q] = (sin a0, sin a1, cos a0 - 1, cos a1 - 1), a = 0.1*omega (rev)
// tblT[q] = same for 10x the angle (r^10).
__global__ __launch_bounds__(256) void tbl_kernel(const float* __restrict__ om,
                                                  float4* __restrict__ tblR,
                                                  float4* __restrict__ tblT) {
    const int q = blockIdx.x * 256 + threadIdx.x;
    if (q < NSTOT * NT) {
        const float a0 = (0.1f * INV2PI) * om[2 * q];
        const float a1 = (0.1f * INV2PI) * om[2 * q + 1];
        tblR[q] = make_float4(fsin(a0), fsin(a1), fcos(a0) - 1.f, fcos(a1) - 1.f);
        const float b0 = 10.f * a0, b1 = 10.f * a1;
        tblT[q] = make_float4(fsin(b0), fsin(b1), fcos(b0) - 1.f, fcos(b1) - 1.f);
    }
}

__global__ __launch_bounds__(NT)
void kuramoto_kernel(const float* __restrict__ lg_,
                     const float* __restrict__ nz_,
                     const float* __restrict__ om_,
                     float* __restrict__ out_,
                     const float4* __restrict__ tblR,
                     const float4* __restrict__ tblT,
                     const float* __restrict__ swp) {
    __shared__ unsigned st[NS_LDS][NT];  // 51,200 B : e pair as half2
    __shared__ float redA[21][8];        // 672 B
    __shared__ float redB[8];            // 32 B

    const int tid = threadIdx.x;
    const size_t base = (size_t)blockIdx.x * V_DIM;
    const float* __restrict__ lg = lg_ + base;
    const float* __restrict__ nz = nz_ + base;
    float* __restrict__ op = out_ + base;

    // ---------------- pass A: sums only, packed accumulators ----------------
    v2f vS[NSTEP], vC[NSTEP];
    #pragma unroll
    for (int t = 0; t < NSTEP; ++t) { vS[t] = v2f{0.f, 0.f}; vC[t] = v2f{0.f, 0.f}; }
    v2f sp0v = {0.f, 0.f};

    #pragma unroll 1
    for (int m = 0; m < NSTOT; ++m) {
        const int e = m * STRIDE + 2 * tid;
        const v2f l = *(const v2f*)(lg + e);
        const v2f n = *(const v2f*)(nz + e);
        const v2f p0 = __builtin_elementwise_fma(v2f{0.1f, 0.1f}, l, n);
        sp0v += p0;
        const float4 tb = tblR[m * NT + tid];
        const v2f ri = {tb.x, tb.y};
        const v2f rr = {1.f + tb.z, 1.f + tb.w};
        v2f s = {fsin(p0.x * INV2PI), fsin(p0.y * INV2PI)};
        v2f c = {fcos(p0.x * INV2PI), fcos(p0.y * INV2PI)};
        #pragma unroll
        for (int t = 0; t < NSTEP; ++t) {
            vS[t] += s; vC[t] += c;
            const v2f u = __builtin_elementwise_fma(s, rr, c * ri);
            const v2f v = __builtin_elementwise_fma(c, rr, -(s * ri));
            s = u; c = v;
        }
    }
    float tts = 0.f, ttd = 0.f;              // tail rotation consts (tid<81)
    if (tid < TAILN) {
        const int e = TAIL_B + tid;
        const float p0 = __builtin_fmaf(0.1f, lg[e], nz[e]);
        sp0v.x += p0;
        float s = fsin(p0 * INV2PI), c = fcos(p0 * INV2PI);
        const float th = (0.1f * INV2PI) * om_[e];
        tts = fsin(th); ttd = fcos(th) - 1.f;
        #pragma unroll
        for (int t = 0; t < NSTEP; ++t) { vS[t].x += s; vC[t].x += c; rot1(s, c, tts, ttd); }
    }

    // ---------------- reduce 21 values (barrier #1) ----------------
    float hS[NSTEP], hC[NSTEP];
    #pragma unroll
    for (int t = 0; t < NSTEP; ++t) { hS[t] = vS[t].x + vS[t].y; hC[t] = vC[t].x + vC[t].y; }
    float sp0 = sp0v.x + sp0v.y;
    #pragma unroll
    for (int off = 32; off > 0; off >>= 1) {
        #pragma unroll
        for (int t = 0; t < NSTEP; ++t) {
            hS[t] += __shfl_xor(hS[t], off, 64);
            hC[t] += __shfl_xor(hC[t], off, 64);
        }
        sp0 += __shfl_xor(sp0, off, 64);
    }
    const int wid = tid >> 6;
    if ((tid & 63) == 0) {
        #pragma unroll
        for (int t = 0; t < NSTEP; ++t) { redA[t][wid] = hS[t]; redA[NSTEP + t][wid] = hC[t]; }
        redA[20][wid] = sp0;
    }
    __syncthreads();
    float dSt[NSTEP], dCt[NSTEP], cM, sM;
    {
        #pragma unroll
        for (int t = 0; t < NSTEP; ++t) {
            float a = 0.f, b = 0.f;
            #pragma unroll
            for (int i = 0; i < NT / 64; ++i) { a += redA[t][i]; b += redA[NSTEP + t][i]; }
            dSt[t] = rfl(DTC * a);
            dCt[t] = rfl(DTC * b);
        }
        float a = 0.f;
        #pragma unroll
        for (int i = 0; i < NT / 64; ++i) a += redA[20][i];
        const float M = (a + swp[0]) / (float)V_DIM;
        cM = rfl(fcos(M * INV2PI)); sM = rfl(fsin(M * INV2PI));
    }

    // ---------------- pass B: Horner eps + z10 table ----------------
    v2f esv = {0.f, 0.f};
    auto passB = [&](int m) -> v2f {
        const int e = m * STRIDE + 2 * tid;
        const v2f l = *(const v2f*)(lg + e);
        const v2f n = *(const v2f*)(nz + e);
        const v2f p0 = __builtin_elementwise_fma(v2f{0.1f, 0.1f}, l, n);
        const v2f s0 = {fsin(p0.x * INV2PI), fsin(p0.y * INV2PI)};
        const v2f c0 = {fcos(p0.x * INV2PI), fcos(p0.y * INV2PI)};
        const float4 tb = tblR[m * NT + tid];
        const v2f ri = {tb.x, tb.y};
        const v2f rr = {1.f + tb.z, 1.f + tb.w};
        // Horner: P = sum_{t=0..9} (dCt[t] - i dSt[t]) r^t
        v2f Pr = {dCt[NSTEP - 1], dCt[NSTEP - 1]};
        v2f Pi = {-dSt[NSTEP - 1], -dSt[NSTEP - 1]};
        #pragma unroll
        for (int t = NSTEP - 2; t >= 0; --t) {
            const v2f a = __builtin_elementwise_fma(-Pi, ri, v2f{dCt[t], dCt[t]});
            const v2f b = __builtin_elementwise_fma(Pi, rr, v2f{-dSt[t], -dSt[t]});
            const v2f Pr2 = __builtin_elementwise_fma(Pr, rr, a);
            const v2f Pi2 = __builtin_elementwise_fma(Pr, ri, b);
            Pr = Pr2; Pi = Pi2;
        }
        // eps = Im(z0 * P) = s0*Re(P) + c0*Im(P)
        const v2f eps = __builtin_elementwise_fma(s0, Pr, c0 * Pi);
        // z10 = z0 * r^10 (table)
        const float4 tt = tblT[m * NT + tid];
        const v2f qi = {tt.x, tt.y};
        const v2f qr = {1.f + tt.z, 1.f + tt.w};
        const v2f s1 = __builtin_elementwise_fma(s0, qr, c0 * qi);
        const v2f c1 = __builtin_elementwise_fma(c0, qr, -(s0 * qi));
        // 1st-order eps rotation (|eps| <= ~0.03, validated r12-r14)
        const v2f s2 = __builtin_elementwise_fma(c1, eps, s1);
        const v2f c2 = __builtin_elementwise_fma(-s1, eps, c1);
        v2f coh = __builtin_elementwise_fma(s2, v2f{sM, sM}, c2 * v2f{cM, cM});
        const v2f ev = {__expf(coh.x), __expf(coh.y)};
        esv += ev;
        return ev;
    };
    #pragma unroll 1
    for (int m = 0; m < NS_LDS; ++m) {
        const v2f ev = passB(m);
        st[m][tid] = __builtin_bit_cast(unsigned, __floats2half2_rn(ev.x, ev.y));
    }
    v2f rst[NS_REG];
    #pragma unroll
    for (int m = NS_LDS; m < NS_LDS + NS_REG; ++m) {
        rst[m - NS_LDS] = passB(m);
        FENCE();
    }
    #pragma unroll 1
    for (int m = NS_LDS + NS_REG; m < NSTOT; ++m) {
        const v2f ev = passB(m);
        *(v2f*)(op + m * STRIDE + 2 * tid) = ev;     // unscaled stash, own slot
    }
    float etail = 0.f;
    if (tid < TAILN) {
        const int e = TAIL_B + tid;
        const float p0 = __builtin_fmaf(0.1f, lg[e], nz[e]);
        float s = fsin(p0 * INV2PI), c = fcos(p0 * INV2PI);
        float ep = 0.f;
        #pragma unroll
        for (int t = 0; t < NSTEP; ++t) {
            ep = __builtin_fmaf(s, dCt[t], ep);
            ep = __builtin_fmaf(-c, dSt[t], ep);
            rot1(s, c, tts, ttd);
        }
        const float s2 = __builtin_fmaf(c, ep, s);
        const float c2 = __builtin_fmaf(-s, ep, c);
        etail = __expf(__builtin_fmaf(c2, cM, s2 * sM));
    }

    // ---------------- esum reduce (barrier #2) ----------------
    float es = esv.x + esv.y + etail;
    #pragma unroll
    for (int off = 32; off > 0; off >>= 1) es += __shfl_xor(es, off, 64);
    if ((tid & 63) == 0) redB[wid] = es;
    __syncthreads();
    float tot = 0.f;
    #pragma unroll
    for (int i = 0; i < NT / 64; ++i) tot += redB[i];
    const float inv = 1.f / tot;

    // ---------------- pass C: scale + store ----------------
    #pragma unroll 1
    for (int m = 0; m < NS_LDS; ++m) {
        const __half2 h = __builtin_bit_cast(__half2, st[m][tid]);
        const v2f ev = {__low2float(h), __high2float(h)};
        *(v2f*)(op + m * STRIDE + 2 * tid) = ev * inv;
    }
    #pragma unroll
    for (int m = NS_LDS; m < NS_LDS + NS_REG; ++m) {
        *(v2f*)(op + m * STRIDE + 2 * tid) = rst[m - NS_LDS] * inv;
    }
    #pragma unroll 1
    for (int m = NS_LDS + NS_REG; m < NSTOT; ++m) {
        float* p = op + m * STRIDE + 2 * tid;
        const v2f ev = *(const v2f*)p;               // own stash, race-free
        *(v2f*)p = ev * inv;
    }
    if (tid < TAILN) op[TAIL_B + tid] = etail * inv;
}

extern "C" void kernel_launch(void* const* d_in, const int* in_sizes, int n_in,
                              void* d_out, int out_size, void* d_ws, size_t ws_size,
                              hipStream_t stream) {
    const float* logits = (const float*)d_in[0];
    const float* omega  = (const float*)d_in[1];  // natural_frequencies [V]
    const float* noise  = (const float*)d_in[2];
    float* out = (float*)d_out;
    float* swp = (float*)d_ws;                               // ws[0] = sum(omega)
    float4* tblR = (float4*)((char*)d_ws + 16);              // 401,408 B
    float4* tblT = (float4*)((char*)d_ws + 16 + 401408);     // 401,408 B
    (void)in_sizes; (void)n_in; (void)out_size; (void)ws_size;

    sw_kernel<<<1, 1024, 0, stream>>>(omega, swp);
    tbl_kernel<<<(NSTOT * NT + 255) / 256, 256, 0, stream>>>(omega, tblR, tblT);
    kuramoto_kernel<<<NROWS, NT, 0, stream>>>(logits, noise, omega, out, tblR, tblT, swp);
}

// Round 16
// 267.347 us; speedup vs baseline: 1.0888x; 1.0888x over previous
//
#include <hip/hip_runtime.h>
#include <hip/hip_fp16.h>

// Kuramoto phase dynamics + coherence softmax. B*S=1024 rows, V=50257, 10 steps.
// Two-pass trajectory scheme (validated r11-r15, absmax 2.38e-7), stateless
// between passes. Round-16: r15's Horner pass B + r14's stash layout + ILP-2.
//  * Stall model (r14/r15: VALUBusy ~40-52%, dur flat): each stripe iteration
//    starts with dependent loads (lg/nz/tbl); at 4 waves/SIMD the ~300cy load
//    latency can't hide behind ~140cy of math. Fix: #pragma unroll 2 on the
//    stripe loops -- two stripes in flight, loads hoisted over math.
//  * Pass B: eps = Im(z0 * P(r)), complex Horner, SGPR coeffs; z10 = z0 * r^10
//    via second table. Pass A: packed v2f accumulators.
//  * Stash: 38 stripes LDS f16 (77.8 KB, 2 blocks/CU), 5 reg, 6 out-slot.
// Partition: 49 pair-stripes of 1024 elems (pairs (2tid,2tid+1)) + 81 tail.
// mean(p_final) = (Sum p0 + Sum omega)/V (sum_i eps_i == 0 identically).

#define V_DIM   50257
#define NROWS   1024
#define NT      512
#define NS_LDS  38                // e stashed in LDS (f16 half2)
#define NS_REG  5                 // e stashed in regs (f32 v2f)
#define NS_OUT  6                 // e stashed unscaled in own out slots
#define NSTOT   (NS_LDS + NS_REG + NS_OUT)   // 49
#define STRIDE  (2 * NT)          // 1024
#define TAIL_B  (NSTOT * STRIDE)  // 50176
#define TAILN   (V_DIM - TAIL_B)  // 81
#define NSTEP   10
#define INV2PI  0.15915494309189535f
#define DTC     (0.1f * (0.1f / (float)V_DIM))

typedef float v2f __attribute__((ext_vector_type(2)));

__device__ __forceinline__ float fsin(float r) { return __builtin_amdgcn_sinf(r); }
__device__ __forceinline__ float fcos(float r) { return __builtin_amdgcn_cosf(r); }
__device__ __forceinline__ float rfl(float x) {
    return __builtin_bit_cast(float, __builtin_amdgcn_readfirstlane(__builtin_bit_cast(int, x)));
}

__device__ __forceinline__ void rot1(float& s, float& c, const float ts, const float td) {
    float u = __builtin_fmaf(s, td, s); u = __builtin_fmaf(c, ts, u);
    float v = __builtin_fmaf(c, td, c); v = __builtin_fmaf(-s, ts, v);
    s = u; c = v;
}

// ---- ws[0] = sum(omega), deterministic single-block reduce ----
__global__ __launch_bounds__(1024) void sw_kernel(const float* __restrict__ om,
                                                  float* __restrict__ ws) {
    __shared__ float red[16];
    const int tid = threadIdx.x;
    float a = 0.f;
    for (int i = tid; i < V_DIM; i += 1024) a += om[i];
    #pragma unroll
    for (int off = 32; off > 0; off >>= 1) a += __shfl_xor(a, off, 64);
    if ((tid & 63) == 0) red[tid >> 6] = a;
    __syncthreads();
    if (tid == 0) {
        float t = 0.f;
        #pragma unroll
        for (int i = 0; i < 16; ++i) t += red[i];
        ws[0] = t;
    }
}

// tblR[q] = (sin a0, sin a1, cos a0 - 1, cos a1 - 1), a = 0.1*omega (rev)
// tblT[q] = same for 10x the angle (r^10).
__global__ __launch_bounds__(256) void tbl_kernel(const float* __restrict__ om,
                                                  float4* __restrict__ tblR,
                                                  float4* __restrict__ tblT) {
    const int q = blockIdx.x * 256 + threadIdx.x;
    if (q < NSTOT * NT) {
        const float a0 = (0.1f * INV2PI) * om[2 * q];
        const float a1 = (0.1f * INV2PI) * om[2 * q + 1];
        tblR[q] = make_float4(fsin(a0), fsin(a1), fcos(a0) - 1.f, fcos(a1) - 1.f);
        const float b0 = 10.f * a0, b1 = 10.f * a1;
        tblT[q] = make_float4(fsin(b0), fsin(b1), fcos(b0) - 1.f, fcos(b1) - 1.f);
    }
}

__global__ __launch_bounds__(NT)
void kuramoto_kernel(const float* __restrict__ lg_,
                     const float* __restrict__ nz_,
                     const float* __restrict__ om_,
                     float* __restrict__ out_,
                     const float4* __restrict__ tblR,
                     const float4* __restrict__ tblT,
                     const float* __restrict__ swp) {
    __shared__ unsigned st[NS_LDS][NT];  // 77,824 B : e pair as half2
    __shared__ float redA[21][8];        // 672 B
    __shared__ float redB[8];            // 32 B

    const int tid = threadIdx.x;
    const size_t base = (size_t)blockIdx.x * V_DIM;
    const float* __restrict__ lg = lg_ + base;
    const float* __restrict__ nz = nz_ + base;
    float* __restrict__ op = out_ + base;

    // ---------------- pass A: sums only, packed accumulators, ILP-2 ----------------
    v2f vS[NSTEP], vC[NSTEP];
    #pragma unroll
    for (int t = 0; t < NSTEP; ++t) { vS[t] = v2f{0.f, 0.f}; vC[t] = v2f{0.f, 0.f}; }
    v2f sp0v = {0.f, 0.f};

    #pragma unroll 2
    for (int m = 0; m < NSTOT; ++m) {
        const int e = m * STRIDE + 2 * tid;
        const v2f l = *(const v2f*)(lg + e);
        const v2f n = *(const v2f*)(nz + e);
        const v2f p0 = __builtin_elementwise_fma(v2f{0.1f, 0.1f}, l, n);
        sp0v += p0;
        const float4 tb = tblR[m * NT + tid];
        const v2f ri = {tb.x, tb.y};
        const v2f rr = {1.f + tb.z, 1.f + tb.w};
        v2f s = {fsin(p0.x * INV2PI), fsin(p0.y * INV2PI)};
        v2f c = {fcos(p0.x * INV2PI), fcos(p0.y * INV2PI)};
        #pragma unroll
        for (int t = 0; t < NSTEP; ++t) {
            vS[t] += s; vC[t] += c;
            const v2f u = __builtin_elementwise_fma(s, rr, c * ri);
            const v2f v = __builtin_elementwise_fma(c, rr, -(s * ri));
            s = u; c = v;
        }
    }
    float tts = 0.f, ttd = 0.f;              // tail rotation consts (tid<81)
    if (tid < TAILN) {
        const int e = TAIL_B + tid;
        const float p0 = __builtin_fmaf(0.1f, lg[e], nz[e]);
        sp0v.x += p0;
        float s = fsin(p0 * INV2PI), c = fcos(p0 * INV2PI);
        const float th = (0.1f * INV2PI) * om_[e];
        tts = fsin(th); ttd = fcos(th) - 1.f;
        #pragma unroll
        for (int t = 0; t < NSTEP; ++t) { vS[t].x += s; vC[t].x += c; rot1(s, c, tts, ttd); }
    }

    // ---------------- reduce 21 values (barrier #1) ----------------
    float hS[NSTEP], hC[NSTEP];
    #pragma unroll
    for (int t = 0; t < NSTEP; ++t) { hS[t] = vS[t].x + vS[t].y; hC[t] = vC[t].x + vC[t].y; }
    float sp0 = sp0v.x + sp0v.y;
    #pragma unroll
    for (int off = 32; off > 0; off >>= 1) {
        #pragma unroll
        for (int t = 0; t < NSTEP; ++t) {
            hS[t] += __shfl_xor(hS[t], off, 64);
            hC[t] += __shfl_xor(hC[t], off, 64);
        }
        sp0 += __shfl_xor(sp0, off, 64);
    }
    const int wid = tid >> 6;
    if ((tid & 63) == 0) {
        #pragma unroll
        for (int t = 0; t < NSTEP; ++t) { redA[t][wid] = hS[t]; redA[NSTEP + t][wid] = hC[t]; }
        redA[20][wid] = sp0;
    }
    __syncthreads();
    float dSt[NSTEP], dCt[NSTEP], cM, sM;
    {
        #pragma unroll
        for (int t = 0; t < NSTEP; ++t) {
            float a = 0.f, b = 0.f;
            #pragma unroll
            for (int i = 0; i < NT / 64; ++i) { a += redA[t][i]; b += redA[NSTEP + t][i]; }
            dSt[t] = rfl(DTC * a);
            dCt[t] = rfl(DTC * b);
        }
        float a = 0.f;
        #pragma unroll
        for (int i = 0; i < NT / 64; ++i) a += redA[20][i];
        const float M = (a + swp[0]) / (float)V_DIM;
        cM = rfl(fcos(M * INV2PI)); sM = rfl(fsin(M * INV2PI));
    }

    // ---------------- pass B: Horner eps + z10 table, ILP-2 ----------------
    v2f esv = {0.f, 0.f};
    auto passB = [&](int m) -> v2f {
        const int e = m * STRIDE + 2 * tid;
        const v2f l = *(const v2f*)(lg + e);
        const v2f n = *(const v2f*)(nz + e);
        const v2f p0 = __builtin_elementwise_fma(v2f{0.1f, 0.1f}, l, n);
        const v2f s0 = {fsin(p0.x * INV2PI), fsin(p0.y * INV2PI)};
        const v2f c0 = {fcos(p0.x * INV2PI), fcos(p0.y * INV2PI)};
        const float4 tb = tblR[m * NT + tid];
        const v2f ri = {tb.x, tb.y};
        const v2f rr = {1.f + tb.z, 1.f + tb.w};
        // Horner: P = sum_{t=0..9} (dCt[t] - i dSt[t]) r^t
        v2f Pr = {dCt[NSTEP - 1], dCt[NSTEP - 1]};
        v2f Pi = {-dSt[NSTEP - 1], -dSt[NSTEP - 1]};
        #pragma unroll
        for (int t = NSTEP - 2; t >= 0; --t) {
            const v2f a = __builtin_elementwise_fma(-Pi, ri, v2f{dCt[t], dCt[t]});
            const v2f b = __builtin_elementwise_fma(Pi, rr, v2f{-dSt[t], -dSt[t]});
            const v2f Pr2 = __builtin_elementwise_fma(Pr, rr, a);
            const v2f Pi2 = __builtin_elementwise_fma(Pr, ri, b);
            Pr = Pr2; Pi = Pi2;
        }
        // eps = Im(z0 * P) = s0*Re(P) + c0*Im(P)
        const v2f eps = __builtin_elementwise_fma(s0, Pr, c0 * Pi);
        // z10 = z0 * r^10 (table)
        const float4 tt = tblT[m * NT + tid];
        const v2f qi = {tt.x, tt.y};
        const v2f qr = {1.f + tt.z, 1.f + tt.w};
        const v2f s1 = __builtin_elementwise_fma(s0, qr, c0 * qi);
        const v2f c1 = __builtin_elementwise_fma(c0, qr, -(s0 * qi));
        // 1st-order eps rotation (|eps| small, validated r12-r15)
        const v2f s2 = __builtin_elementwise_fma(c1, eps, s1);
        const v2f c2 = __builtin_elementwise_fma(-s1, eps, c1);
        v2f coh = __builtin_elementwise_fma(s2, v2f{sM, sM}, c2 * v2f{cM, cM});
        const v2f ev = {__expf(coh.x), __expf(coh.y)};
        esv += ev;
        return ev;
    };
    #pragma unroll 2
    for (int m = 0; m < NS_LDS; ++m) {
        const v2f ev = passB(m);
        st[m][tid] = __builtin_bit_cast(unsigned, __floats2half2_rn(ev.x, ev.y));
    }
    v2f rst[NS_REG];
    #pragma unroll
    for (int m = NS_LDS; m < NS_LDS + NS_REG; ++m) {
        rst[m - NS_LDS] = passB(m);
    }
    #pragma unroll 2
    for (int m = NS_LDS + NS_REG; m < NSTOT; ++m) {
        const v2f ev = passB(m);
        *(v2f*)(op + m * STRIDE + 2 * tid) = ev;     // unscaled stash, own slot
    }
    float etail = 0.f;
    if (tid < TAILN) {
        const int e = TAIL_B + tid;
        const float p0 = __builtin_fmaf(0.1f, lg[e], nz[e]);
        float s = fsin(p0 * INV2PI), c = fcos(p0 * INV2PI);
        float ep = 0.f;
        #pragma unroll
        for (int t = 0; t < NSTEP; ++t) {
            ep = __builtin_fmaf(s, dCt[t], ep);
            ep = __builtin_fmaf(-c, dSt[t], ep);
            rot1(s, c, tts, ttd);
        }
        const float s2 = __builtin_fmaf(c, ep, s);
        const float c2 = __builtin_fmaf(-s, ep, c);
        etail = __expf(__builtin_fmaf(c2, cM, s2 * sM));
    }

    // ---------------- esum reduce (barrier #2) ----------------
    float es = esv.x + esv.y + etail;
    #pragma unroll
    for (int off = 32; off > 0; off >>= 1) es += __shfl_xor(es, off, 64);
    if ((tid & 63) == 0) redB[wid] = es;
    __syncthreads();
    float tot = 0.f;
    #pragma unroll
    for (int i = 0; i < NT / 64; ++i) tot += redB[i];
    const float inv = 1.f / tot;

    // ---------------- pass C: scale + store ----------------
    #pragma unroll 2
    for (int m = 0; m < NS_LDS; ++m) {
        const __half2 h = __builtin_bit_cast(__half2, st[m][tid]);
        const v2f ev = {__low2float(h), __high2float(h)};
        *(v2f*)(op + m * STRIDE + 2 * tid) = ev * inv;
    }
    #pragma unroll
    for (int m = NS_LDS; m < NS_LDS + NS_REG; ++m) {
        *(v2f*)(op + m * STRIDE + 2 * tid) = rst[m - NS_LDS] * inv;
    }
    #pragma unroll 2
    for (int m = NS_LDS + NS_REG; m < NSTOT; ++m) {
        float* p = op + m * STRIDE + 2 * tid;
        const v2f ev = *(const v2f*)p;               // own stash, race-free
        *(v2f*)p = ev * inv;
    }
    if (tid < TAILN) op[TAIL_B + tid] = etail * inv;
}

extern "C" void kernel_launch(void* const* d_in, const int* in_sizes, int n_in,
                              void* d_out, int out_size, void* d_ws, size_t ws_size,
                              hipStream_t stream) {
    const float* logits = (const float*)d_in[0];
    const float* omega  = (const float*)d_in[1];  // natural_frequencies [V]
    const float* noise  = (const float*)d_in[2];
    float* out = (float*)d_out;
    float* swp = (float*)d_ws;                               // ws[0] = sum(omega)
    float4* tblR = (float4*)((char*)d_ws + 16);              // 401,408 B
    float4* tblT = (float4*)((char*)d_ws + 16 + 401408);     // 401,408 B
    (void)in_sizes; (void)n_in; (void)out_size; (void)ws_size;

    sw_kernel<<<1, 1024, 0, stream>>>(omega, swp);
    tbl_kernel<<<(NSTOT * NT + 255) / 256, 256, 0, stream>>>(omega, tblR, tblT);
    kuramoto_kernel<<<NROWS, NT, 0, stream>>>(logits, noise, omega, out, tblR, tblT, swp);
}

// Round 17
// 237.052 us; speedup vs baseline: 1.2279x; 1.1278x over previous
//
#include <hip/hip_runtime.h>
#include <hip/hip_fp16.h>

// Kuramoto phase dynamics + coherence softmax. B*S=1024 rows, V=50257, 10 steps.
// Two-pass trajectory scheme (validated r11-r16, absmax 2.38e-7), stateless.
// Round-17: pass B via per-row F/G TABLE + pass A via Chebyshev recurrence.
//   eps_j = s0_j*F(th_j) + c0_j*G(th_j),  th = 0.1*omega,
//   F(th) = sum_t dCt cos(t th) + dSt sin(t th),
//   G(th) = sum_t dCt sin(t th) - dSt cos(t th)  -- row-wide coefficients, so
//   F,G are tabulated on a 512-pt LDS grid over omega in [-8,8] (1 pt/thread,
//   Chebyshev recurrence) right after the reduce. Pass B per element: lerp
//   F,G; eps = s0*F + c0*G; coh = cos(p0 + omega - M + eps) DIRECTLY (exact,
//   replaces Horner + z10 + 1st-order rotation + cM/sM). Interp err ~4e-6 rad
//   -> ~2e-10 on out. Pass A: s_{t+1} = 2cos(th)*s_t - s_{t-1} (2 pk-fma/step
//   vs 4fma+2mul). mean M = (Sum p0 + Sum omega)/V (sum_j eps_j == 0).
// Stash: 36 stripes LDS f16 e-pairs (73.7 KB) + 5 reg + 8 out-slot; LDS total
// 78.5 KB -> 2 blocks/CU. ILP-2 on stripe loops (r16 win).

#define V_DIM   50257
#define NROWS   1024
#define NT      512
#define NS_LDS  36                // e stashed in LDS (f16 half2)
#define NS_REG  5                 // e stashed in regs (f32 v2f)
#define NS_OUT  8                 // e stashed unscaled in own out slots
#define NSTOT   (NS_LDS + NS_REG + NS_OUT)   // 49
#define STRIDE  (2 * NT)          // 1024
#define TAIL_B  (NSTOT * STRIDE)  // 50176
#define TAILN   (V_DIM - TAIL_B)  // 81
#define NSTEP   10
#define KGRID   512
#define INV2PI  0.15915494309189535f
#define DTC     (0.1f * (0.1f / (float)V_DIM))

typedef float v2f __attribute__((ext_vector_type(2)));

__device__ __forceinline__ float fsin(float r) { return __builtin_amdgcn_sinf(r); }
__device__ __forceinline__ float fcos(float r) { return __builtin_amdgcn_cosf(r); }
__device__ __forceinline__ float rfl(float x) {
    return __builtin_bit_cast(float, __builtin_amdgcn_readfirstlane(__builtin_bit_cast(int, x)));
}

// ---- ws[0] = sum(omega), deterministic single-block reduce ----
__global__ __launch_bounds__(1024) void sw_kernel(const float* __restrict__ om,
                                                  float* __restrict__ ws) {
    __shared__ float red[16];
    const int tid = threadIdx.x;
    float a = 0.f;
    for (int i = tid; i < V_DIM; i += 1024) a += om[i];
    #pragma unroll
    for (int off = 32; off > 0; off >>= 1) a += __shfl_xor(a, off, 64);
    if ((tid & 63) == 0) red[tid >> 6] = a;
    __syncthreads();
    if (tid == 0) {
        float t = 0.f;
        #pragma unroll
        for (int i = 0; i < 16; ++i) t += red[i];
        ws[0] = t;
    }
}

// tblR[q] = (sin a0, sin a1, cos a0 - 1, cos a1 - 1), a = 0.1*omega (rev units)
__global__ __launch_bounds__(256) void tbl_kernel(const float* __restrict__ om,
                                                  float4* __restrict__ tblR) {
    const int q = blockIdx.x * 256 + threadIdx.x;
    if (q < NSTOT * NT) {
        const float a0 = (0.1f * INV2PI) * om[2 * q];
        const float a1 = (0.1f * INV2PI) * om[2 * q + 1];
        tblR[q] = make_float4(fsin(a0), fsin(a1), fcos(a0) - 1.f, fcos(a1) - 1.f);
    }
}

__global__ __launch_bounds__(NT)
void kuramoto_kernel(const float* __restrict__ lg_,
                     const float* __restrict__ nz_,
                     const float* __restrict__ om_,
                     float* __restrict__ out_,
                     const float4* __restrict__ tblR,
                     const float* __restrict__ swp) {
    __shared__ unsigned st[NS_LDS][NT];  // 73,728 B : e pair as half2
    __shared__ float2 FG[KGRID];         // 4,096 B  : (F,G) over omega grid
    __shared__ float redA[21][8];        // 672 B
    __shared__ float redB[8];            // 32 B

    const int tid = threadIdx.x;
    const size_t base = (size_t)blockIdx.x * V_DIM;
    const float* __restrict__ lg = lg_ + base;
    const float* __restrict__ nz = nz_ + base;
    float* __restrict__ op = out_ + base;

    // ---------------- pass A: S_t,C_t sums via Chebyshev, no state ----------------
    v2f vS[NSTEP], vC[NSTEP];
    #pragma unroll
    for (int t = 0; t < NSTEP; ++t) { vS[t] = v2f{0.f, 0.f}; vC[t] = v2f{0.f, 0.f}; }
    v2f sp0v = {0.f, 0.f};

    #pragma unroll 2
    for (int m = 0; m < NSTOT; ++m) {
        const int e = m * STRIDE + 2 * tid;
        const v2f l = *(const v2f*)(lg + e);
        const v2f n = *(const v2f*)(nz + e);
        const v2f p0 = __builtin_elementwise_fma(v2f{0.1f, 0.1f}, l, n);
        sp0v += p0;
        const float4 tb = tblR[m * NT + tid];
        const v2f ts = {tb.x, tb.y}, td = {tb.z, tb.w};
        const v2f k = __builtin_elementwise_fma(v2f{2.f, 2.f}, td, v2f{2.f, 2.f}); // 2cos
        v2f sp = {fsin(p0.x * INV2PI), fsin(p0.y * INV2PI)};
        v2f cp = {fcos(p0.x * INV2PI), fcos(p0.y * INV2PI)};
        v2f sc = __builtin_elementwise_fma(sp, td, __builtin_elementwise_fma(cp, ts, sp));
        v2f cc = __builtin_elementwise_fma(cp, td, __builtin_elementwise_fma(-sp, ts, cp));
        vS[0] += sp; vC[0] += cp;
        vS[1] += sc; vC[1] += cc;
        #pragma unroll
        for (int t = 2; t < NSTEP; ++t) {
            const v2f sn = __builtin_elementwise_fma(k, sc, -sp);
            const v2f cn = __builtin_elementwise_fma(k, cc, -cp);
            sp = sc; cp = cc; sc = sn; cc = cn;
            vS[t] += sn; vC[t] += cn;
        }
    }
    if (tid < TAILN) {   // tail, scalar
        const int e = TAIL_B + tid;
        const float p0 = __builtin_fmaf(0.1f, lg[e], nz[e]);
        sp0v.x += p0;
        const float th = (0.1f * INV2PI) * om_[e];
        const float ts = fsin(th), td = fcos(th) - 1.f;
        const float k = 2.f + 2.f * td;
        float sp = fsin(p0 * INV2PI), cp = fcos(p0 * INV2PI);
        float sc = __builtin_fmaf(sp, td, __builtin_fmaf(cp, ts, sp));
        float cc = __builtin_fmaf(cp, td, __builtin_fmaf(-sp, ts, cp));
        vS[0].x += sp; vC[0].x += cp; vS[1].x += sc; vC[1].x += cc;
        #pragma unroll
        for (int t = 2; t < NSTEP; ++t) {
            const float sn = __builtin_fmaf(k, sc, -sp);
            const float cn = __builtin_fmaf(k, cc, -cp);
            sp = sc; cp = cc; sc = sn; cc = cn;
            vS[t].x += sn; vC[t].x += cn;
        }
    }

    // ---------------- reduce 21 values (barrier #1) ----------------
    float hS[NSTEP], hC[NSTEP];
    #pragma unroll
    for (int t = 0; t < NSTEP; ++t) { hS[t] = vS[t].x + vS[t].y; hC[t] = vC[t].x + vC[t].y; }
    float sp0 = sp0v.x + sp0v.y;
    #pragma unroll
    for (int off = 32; off > 0; off >>= 1) {
        #pragma unroll
        for (int t = 0; t < NSTEP; ++t) {
            hS[t] += __shfl_xor(hS[t], off, 64);
            hC[t] += __shfl_xor(hC[t], off, 64);
        }
        sp0 += __shfl_xor(sp0, off, 64);
    }
    const int wid = tid >> 6;
    if ((tid & 63) == 0) {
        #pragma unroll
        for (int t = 0; t < NSTEP; ++t) { redA[t][wid] = hS[t]; redA[NSTEP + t][wid] = hC[t]; }
        redA[20][wid] = sp0;
    }
    __syncthreads();
    float dSt[NSTEP], dCt[NSTEP], M;
    {
        #pragma unroll
        for (int t = 0; t < NSTEP; ++t) {
            float a = 0.f, b = 0.f;
            #pragma unroll
            for (int i = 0; i < NT / 64; ++i) { a += redA[t][i]; b += redA[NSTEP + t][i]; }
            dSt[t] = rfl(DTC * a);
            dCt[t] = rfl(DTC * b);
        }
        float a = 0.f;
        #pragma unroll
        for (int i = 0; i < NT / 64; ++i) a += redA[20][i];
        M = rfl((a + swp[0]) / (float)V_DIM);
    }

    // ---------------- build F/G table (1 grid point per thread) ----------------
    {
        const float wg = -8.f + (16.f / (float)KGRID) * (float)tid;   // omega grid
        const float threv = (0.1f * INV2PI) * wg;
        const float s1 = fsin(threv), c1 = fcos(threv);
        const float k = 2.f * c1;
        float F = dCt[0];                 // t=0: cos=1, sin=0
        float G = -dSt[0];
        float cp = 1.f, sp = 0.f, cc = c1, sc = s1;
        #pragma unroll
        for (int t = 1; t < NSTEP; ++t) {
            F += dCt[t] * cc + dSt[t] * sc;
            G += dCt[t] * sc - dSt[t] * cc;
            const float cn = __builtin_fmaf(k, cc, -cp);
            const float sn = __builtin_fmaf(k, sc, -sp);
            cp = cc; sp = sc; cc = cn; sc = sn;
        }
        FG[tid] = make_float2(F, G);
    }
    __syncthreads();   // barrier #1.5: FG visible

    // ---------------- pass B: lerp F/G, direct cos ----------------
    v2f esv = {0.f, 0.f};
    auto passB = [&](int m) -> v2f {
        const int e = m * STRIDE + 2 * tid;
        const v2f l = *(const v2f*)(lg + e);
        const v2f n = *(const v2f*)(nz + e);
        const v2f w = *(const v2f*)(om_ + e);
        const v2f p0 = __builtin_elementwise_fma(v2f{0.1f, 0.1f}, l, n);
        const v2f s0 = {fsin(p0.x * INV2PI), fsin(p0.y * INV2PI)};
        const v2f c0 = {fcos(p0.x * INV2PI), fcos(p0.y * INV2PI)};
        // table lookup per component
        const float ux = __builtin_fmaf(w.x, (float)KGRID / 16.f, (float)KGRID / 2.f);
        const float uy = __builtin_fmaf(w.y, (float)KGRID / 16.f, (float)KGRID / 2.f);
        int ix = (int)ux; ix = ix < 0 ? 0 : (ix > KGRID - 2 ? KGRID - 2 : ix);
        int iy = (int)uy; iy = iy < 0 ? 0 : (iy > KGRID - 2 ? KGRID - 2 : iy);
        const float fx = ux - (float)ix, fy = uy - (float)iy;
        const float2 ax = FG[ix], bx = FG[ix + 1];
        const float2 ay = FG[iy], by = FG[iy + 1];
        const float Fx = __builtin_fmaf(fx, bx.x - ax.x, ax.x);
        const float Gx = __builtin_fmaf(fx, bx.y - ax.y, ax.y);
        const float Fy = __builtin_fmaf(fy, by.x - ay.x, ay.x);
        const float Gy = __builtin_fmaf(fy, by.y - ay.y, ay.y);
        const v2f eps = {__builtin_fmaf(s0.x, Fx, c0.x * Gx),
                         __builtin_fmaf(s0.y, Fy, c0.y * Gy)};
        // coh = cos(p0 + omega - M + eps), exact
        v2f psi = (p0 + w) + (eps - v2f{M, M});
        const v2f coh = {fcos(psi.x * INV2PI), fcos(psi.y * INV2PI)};
        const v2f ev = {__expf(coh.x), __expf(coh.y)};
        esv += ev;
        return ev;
    };
    #pragma unroll 2
    for (int m = 0; m < NS_LDS; ++m) {
        const v2f ev = passB(m);
        st[m][tid] = __builtin_bit_cast(unsigned, __floats2half2_rn(ev.x, ev.y));
    }
    v2f rst[NS_REG];
    #pragma unroll
    for (int m = NS_LDS; m < NS_LDS + NS_REG; ++m) {
        rst[m - NS_LDS] = passB(m);
    }
    #pragma unroll 2
    for (int m = NS_LDS + NS_REG; m < NSTOT; ++m) {
        const v2f ev = passB(m);
        *(v2f*)(op + m * STRIDE + 2 * tid) = ev;     // unscaled stash, own slot
    }
    float etail = 0.f;
    if (tid < TAILN) {
        const int e = TAIL_B + tid;
        const float p0 = __builtin_fmaf(0.1f, lg[e], nz[e]);
        const float w = om_[e];
        const float s0 = fsin(p0 * INV2PI), c0 = fcos(p0 * INV2PI);
        const float u = __builtin_fmaf(w, (float)KGRID / 16.f, (float)KGRID / 2.f);
        int i = (int)u; i = i < 0 ? 0 : (i > KGRID - 2 ? KGRID - 2 : i);
        const float f = u - (float)i;
        const float2 a = FG[i], b = FG[i + 1];
        const float F = __builtin_fmaf(f, b.x - a.x, a.x);
        const float G = __builtin_fmaf(f, b.y - a.y, a.y);
        const float eps = __builtin_fmaf(s0, F, c0 * G);
        const float psi = p0 + w - M + eps;
        etail = __expf(fcos(psi * INV2PI));
    }

    // ---------------- esum reduce (barrier #2) ----------------
    float es = esv.x + esv.y + etail;
    #pragma unroll
    for (int off = 32; off > 0; off >>= 1) es += __shfl_xor(es, off, 64);
    if ((tid & 63) == 0) redB[wid] = es;
    __syncthreads();
    float tot = 0.f;
    #pragma unroll
    for (int i = 0; i < NT / 64; ++i) tot += redB[i];
    const float inv = 1.f / tot;

    // ---------------- pass C: scale + store ----------------
    #pragma unroll 2
    for (int m = 0; m < NS_LDS; ++m) {
        const __half2 h = __builtin_bit_cast(__half2, st[m][tid]);
        const v2f ev = {__low2float(h), __high2float(h)};
        *(v2f*)(op + m * STRIDE + 2 * tid) = ev * inv;
    }
    #pragma unroll
    for (int m = NS_LDS; m < NS_LDS + NS_REG; ++m) {
        *(v2f*)(op + m * STRIDE + 2 * tid) = rst[m - NS_LDS] * inv;
    }
    #pragma unroll 2
    for (int m = NS_LDS + NS_REG; m < NSTOT; ++m) {
        float* p = op + m * STRIDE + 2 * tid;
        const v2f ev = *(const v2f*)p;               // own stash, race-free
        *(v2f*)p = ev * inv;
    }
    if (tid < TAILN) op[TAIL_B + tid] = etail * inv;
}

extern "C" void kernel_launch(void* const* d_in, const int* in_sizes, int n_in,
                              void* d_out, int out_size, void* d_ws, size_t ws_size,
                              hipStream_t stream) {
    const float* logits = (const float*)d_in[0];
    const float* omega  = (const float*)d_in[1];  // natural_frequencies [V]
    const float* noise  = (const float*)d_in[2];
    float* out = (float*)d_out;
    float* swp = (float*)d_ws;                               // ws[0] = sum(omega)
    float4* tblR = (float4*)((char*)d_ws + 16);              // 401,408 B
    (void)in_sizes; (void)n_in; (void)out_size; (void)ws_size;

    sw_kernel<<<1, 1024, 0, stream>>>(omega, swp);
    tbl_kernel<<<(NSTOT * NT + 255) / 256, 256, 0, stream>>>(omega, tblR);
    kuramoto_kernel<<<NROWS, NT, 0, stream>>>(logits, noise, omega, out, tblR, swp);
}